// Round 1
// baseline (1931.481 us; speedup 1.0000x reference)
//
#include <hip/hip_runtime.h>
#include <stdint.h>
#include <stddef.h>

#define NUM_EXPERT 16
#define IN_FEAT 2048
#define OUT_FEAT 8192
#define TOTAL_TOKENS 8192

#define BM 128
#define BN 128
#define BK 32
#define KSTEPS (IN_FEAT / BK)
#define MAX_SLOTS 80   // sum ceil(c_e/128) <= (8192 + 16*127)/128 = 79.875 -> 79

typedef __attribute__((ext_vector_type(8))) short short8;     // 8 bf16 = 4 VGPRs
typedef __attribute__((ext_vector_type(4))) float floatx4;
typedef __attribute__((ext_vector_type(4))) uint32_t uintx4;

// pack two fp32 -> two bf16 (round-half-up: +0x8000 then take high 16;
// v_perm_b32 combines the two high halves in one instruction)
__device__ __forceinline__ uint32_t pk_bf16(float a, float b) {
    uint32_t ua = __float_as_uint(a) + 0x8000u;
    uint32_t ub = __float_as_uint(b) + 0x8000u;
    return __builtin_amdgcn_perm(ub, ua, 0x07060302u);
}

// async 16B global->LDS (wave-uniform LDS base + lane*16)
__device__ __forceinline__ void cp16_to_lds(const void* g, void* l) {
    __builtin_amdgcn_global_load_lds(
        (const __attribute__((address_space(1))) uint32_t*)g,
        (__attribute__((address_space(3))) uint32_t*)l, 16, 0, 0);
}

// pre-pass: inp fp32 [8192 x 2048] -> bf16 in ws
__global__ __launch_bounds__(256) void cvt_a_kernel(const float* __restrict__ inp,
                                                    uint16_t* __restrict__ dst) {
    size_t base = ((size_t)blockIdx.x * 256 + threadIdx.x) * 8;
    floatx4 f0 = ((const floatx4*)(inp + base))[0];
    floatx4 f1 = ((const floatx4*)(inp + base))[1];
    uintx4 d;
    d.x = pk_bf16(f0.x, f0.y);
    d.y = pk_bf16(f0.z, f0.w);
    d.z = pk_bf16(f1.x, f1.y);
    d.w = pk_bf16(f1.z, f1.w);
    *(uintx4*)(dst + base) = d;
}

// Grouped GEMM: out[t][o] = sum_k inp[t][k] * W[e][o][k], token groups contiguous.
// A LDS layout: row-major [128 rows][32 k] bf16 (chunk c = r*4 + p, p = k/8)
// B LDS layout: k-outer  (chunk c = p*128 + n)  -- both bank-uniform
template <bool A_IN_WS>
__global__ __launch_bounds__(256)
void moe_gemm(const float* __restrict__ W,
              const float* __restrict__ inp,
              const uint16_t* __restrict__ Abf,
              const int* __restrict__ cnt_raw,
              float* __restrict__ out) {
    const int nt = blockIdx.x;    // n-tile 0..63
    const int slot = blockIdx.y;  // m-slot 0..79

    // ---- counts dtype autodetect (int32 expected; int64 if JAX x64) ----
    int sum32 = 0;
#pragma unroll
    for (int i = 0; i < NUM_EXPERT; ++i) sum32 += cnt_raw[i];
    const int idxmul = (sum32 == TOTAL_TOKENS) ? 1 : 2;  // int64 little-endian low words

    // ---- slot -> (expert, local tile) ----
    int e = -1, lt = 0, cnt = 0, row0 = 0;
    {
        int off = 0, tacc = 0;
#pragma unroll
        for (int i = 0; i < NUM_EXPERT; ++i) {
            int c = cnt_raw[i * idxmul];
            int t = (c + BM - 1) >> 7;
            if (e < 0 && slot < tacc + t) {
                e = i; lt = slot - tacc; cnt = c; row0 = off + lt * BM;
            }
            tacc += t; off += c;
        }
    }
    if (e < 0) return;  // slot beyond total tiles

    const int tid = threadIdx.x;
    const int lane = tid & 63;
    const int w = tid >> 6;   // wave 0..3
    const int wm = w >> 1;    // wave row  (64-row half)
    const int wn = w & 1;     // wave col  (64-col half)
    const int l15 = lane & 15;
    const int l4 = lane >> 4;

    __shared__ uint16_t Abuf[BM * BK];  // 8 KiB
    __shared__ uint16_t Bbuf[BN * BK];  // 8 KiB

    // ---- B staging: thread -> (row n = tid/2, parts {2*(tid&1), +1}) ----
    const int bn = tid >> 1;
    const int bp = (tid & 1) * 2;
    const float* bg = W + ((size_t)e * OUT_FEAT + (size_t)nt * BN + bn) * IN_FEAT + bp * 8;
    uintx4* bl0 = (uintx4*)(Bbuf + ((size_t)(bp)     * BN + bn) * 8);
    uintx4* bl1 = (uintx4*)(Bbuf + ((size_t)(bp + 1) * BN + bn) * 8);

    // ---- A staging setup ----
    const uint16_t* ag0 = nullptr; const uint16_t* ag1 = nullptr;
    uint16_t* al0 = nullptr; uint16_t* al1 = nullptr;
    const float* ia = nullptr; uintx4* ial0 = nullptr; uintx4* ial1 = nullptr;
    if constexpr (A_IN_WS) {
        // global_load_lds: inst i covers chunks i*256 + w*64 + lane
        int c0 = tid, c1 = 256 + tid;
        int r0 = c0 >> 2, p0 = c0 & 3;
        int r1 = c1 >> 2, p1 = c1 & 3;
        int gr0 = min(row0 + r0, TOTAL_TOKENS - 1);
        int gr1 = min(row0 + r1, TOTAL_TOKENS - 1);
        ag0 = Abf + (size_t)gr0 * IN_FEAT + p0 * 8;
        ag1 = Abf + (size_t)gr1 * IN_FEAT + p1 * 8;
        al0 = Abuf + (size_t)(w * 64) * 8;          // wave-uniform base
        al1 = Abuf + (size_t)(256 + w * 64) * 8;
    } else {
        int ar = tid >> 1;
        int ap = (tid & 1) * 2;
        int gr = min(row0 + ar, TOTAL_TOKENS - 1);
        ia = inp + (size_t)gr * IN_FEAT + ap * 8;
        ial0 = (uintx4*)(Abuf + (size_t)(ar * 4 + ap) * 8);
        ial1 = (uintx4*)(Abuf + (size_t)(ar * 4 + ap + 1) * 8);
    }

    // ---- fragment read indices (constant over K loop) ----
    const short8* Ach = (const short8*)Abuf;
    const short8* Bch = (const short8*)Bbuf;
    int aidx[4], bidx[4];
#pragma unroll
    for (int i = 0; i < 4; ++i) aidx[i] = ((wm * 64 + i * 16 + l15) << 2) + l4;
#pragma unroll
    for (int j = 0; j < 4; ++j) bidx[j] = (l4 << 7) + (wn * 64 + j * 16 + l15);

    floatx4 acc[4][4] = {};

    for (int ks = 0; ks < KSTEPS; ++ks) {
        // B-tile fp32 loads (no LDS dependency -> issue before barrier)
        floatx4 f0 = ((const floatx4*)bg)[0];
        floatx4 f1 = ((const floatx4*)bg)[1];
        floatx4 f2 = ((const floatx4*)bg)[2];
        floatx4 f3 = ((const floatx4*)bg)[3];
        floatx4 g0 = {}, g1 = {}, g2 = {}, g3 = {};
        if constexpr (!A_IN_WS) {
            g0 = ((const floatx4*)ia)[0];
            g1 = ((const floatx4*)ia)[1];
            g2 = ((const floatx4*)ia)[2];
            g3 = ((const floatx4*)ia)[3];
        }

        __syncthreads();  // previous iter's frag reads done

        if constexpr (A_IN_WS) {
            cp16_to_lds(ag0, al0);
            cp16_to_lds(ag1, al1);
            ag0 += BK; ag1 += BK;
        } else {
            uintx4 da0, da1;
            da0.x = pk_bf16(g0.x, g0.y); da0.y = pk_bf16(g0.z, g0.w);
            da0.z = pk_bf16(g1.x, g1.y); da0.w = pk_bf16(g1.z, g1.w);
            da1.x = pk_bf16(g2.x, g2.y); da1.y = pk_bf16(g2.z, g2.w);
            da1.z = pk_bf16(g3.x, g3.y); da1.w = pk_bf16(g3.z, g3.w);
            *ial0 = da0; *ial1 = da1;
            ia += BK;
        }
        {
            uintx4 d0, d1;
            d0.x = pk_bf16(f0.x, f0.y); d0.y = pk_bf16(f0.z, f0.w);
            d0.z = pk_bf16(f1.x, f1.y); d0.w = pk_bf16(f1.z, f1.w);
            d1.x = pk_bf16(f2.x, f2.y); d1.y = pk_bf16(f2.z, f2.w);
            d1.z = pk_bf16(f3.x, f3.y); d1.w = pk_bf16(f3.z, f3.w);
            *bl0 = d0; *bl1 = d1;
        }
        bg += BK;

        __syncthreads();  // staging visible (compiler drains vmcnt+lgkmcnt)

        short8 av[4], bv[4];
#pragma unroll
        for (int i = 0; i < 4; ++i) av[i] = Ach[aidx[i]];
#pragma unroll
        for (int j = 0; j < 4; ++j) bv[j] = Bch[bidx[j]];
#pragma unroll
        for (int i = 0; i < 4; ++i)
#pragma unroll
            for (int j = 0; j < 4; ++j)
                acc[i][j] = __builtin_amdgcn_mfma_f32_16x16x32_bf16(av[i], bv[j], acc[i][j], 0, 0, 0);
    }

    // ---- epilogue: C/D layout col = lane&15, row = (lane>>4)*4 + reg ----
    const int cnt_loc = cnt - lt * BM;  // valid rows in this tile (1..128)
    const size_t col = (size_t)nt * BN + wn * 64 + l15;
#pragma unroll
    for (int i = 0; i < 4; ++i) {
        int rb = wm * 64 + i * 16 + l4 * 4;
#pragma unroll
        for (int reg = 0; reg < 4; ++reg) {
            int r = rb + reg;
            if (r < cnt_loc) {
                float* rp = out + (size_t)(row0 + r) * OUT_FEAT + col;
                rp[0]  = acc[i][0][reg];
                rp[16] = acc[i][1][reg];
                rp[32] = acc[i][2][reg];
                rp[48] = acc[i][3][reg];
            }
        }
    }
}

extern "C" void kernel_launch(void* const* d_in, const int* in_sizes, int n_in,
                              void* d_out, int out_size, void* d_ws, size_t ws_size,
                              hipStream_t stream) {
    const float* inp = (const float*)d_in[0];
    const float* W = (const float*)d_in[1];
    const int* counts = (const int*)d_in[2];
    float* out = (float*)d_out;

    const size_t abytes = (size_t)TOTAL_TOKENS * IN_FEAT * sizeof(uint16_t);  // 32 MiB
    dim3 grid(OUT_FEAT / BN, MAX_SLOTS);

    if (ws_size >= abytes) {
        uint16_t* Abf = (uint16_t*)d_ws;
        int nblk = (int)(((size_t)TOTAL_TOKENS * IN_FEAT) / (256 * 8));  // 8192
        cvt_a_kernel<<<nblk, 256, 0, stream>>>(inp, Abf);
        moe_gemm<true><<<grid, 256, 0, stream>>>(W, inp, Abf, counts, out);
    } else {
        moe_gemm<false><<<grid, 256, 0, stream>>>(W, inp, nullptr, counts, out);
    }
}